// Round 25
// baseline (184.442 us; speedup 1.0000x reference)
//
#include <hip/hip_runtime.h>

typedef unsigned short u16;
typedef unsigned int   u32;
typedef __bf16 bf16x8 __attribute__((ext_vector_type(8)));
typedef float  f32x4  __attribute__((ext_vector_type(4)));

#define DEVI __device__ __forceinline__

DEVI u16 f2bf(float f) {
    union { float f; u32 u; } c; c.f = f;
    u32 u = c.u;
    u32 r = (u + 0x7fffu + ((u >> 16) & 1u)) >> 16;
    return (u16)r;
}
DEVI float bf2f(u16 v) {
    union { u32 u; float f; } c; c.u = ((u32)v) << 16;
    return c.f;
}

DEVI void gload16(const void* g, void* l) {
    __builtin_amdgcn_global_load_lds(
        (const __attribute__((address_space(1))) void*)g,
        (__attribute__((address_space(3))) void*)l, 16, 0, 0);
}

// ------------- 128x128 GEMM, BK=32, 256 threads, 4 blocks/CU -------------
// r25: r24's regression was bank conflicts (8.4M), not the 4-block idea.
// [128][32] rows are 64B = HALF a bank sweep -> bank = 16*(row&1) +
// 4*chunk (mod 32); the r17 swizzle (chunk^row&3) collides rows r, r+4.
// Correct involution for 64B rows: s(row) = (row>>1)&3. Quarter-wave spans
// 16*(r&1)+4*((r>>1)&3) = 8 distinct 4-bank spans x2 lanes = 2 words/bank
// (floor; verified exhaustively). Stage source ks=((tid&3)^((tid>>3)&3))<<3
// (rows r, r+64 share (r>>1)&3); read kA=((lane>>4)^((lane>>1)&3))<<3
// (frag rows = 16a+(lane&15) -> (row>>1)&3 = (lane>>1)&3).
// Buffer q at q*8192 u16 (16KB): A [128][32] @+0, B @+4096. One
// __syncthreads per K-tile; stage T+1 into the opposite buffer; 4
// independent blocks/CU give 4 unsynced phase domains (port/MFMA overlap).

#define SP1     __builtin_amdgcn_s_setprio(1)
#define SP0     __builtin_amdgcn_s_setprio(0)

// stage one 8KB half ([128 rows][32 K] bf16) with 256 threads: 2 x 16B.
DEVI void stage32(const u16* g, u16* slot, int tid) {
    const int r = tid >> 2;                                  // 0..63
    const int ks = (((tid & 3) ^ ((tid >> 3) & 3)) << 3);    // s(r)=(r>>1)&3
    gload16(g + (long)r * 1024 + ks, slot + tid * 8);
    gload16(g + (long)(r + 64) * 1024 + ks, slot + 2048 + tid * 8);
}

DEVI f32x4 mfma(const bf16x8& a, const bf16x8& b, const f32x4& c) {
    return __builtin_amdgcn_mfma_f32_16x16x32_bf16(a, b, c, 0, 0, 0);
}

#define NOP do {} while (0)
#define TCLOSE { __syncthreads(); }

// one K-tile (BK=32) from buffer base Q: stage, 8 reads, 16 MFMA, sync.
#define TILE(Q, STG, SYNC)                                                   \
    {                                                                        \
        STG;                                                                 \
        bf16x8 bh[4], aa[4];                                                 \
        _Pragma("unroll")                                                    \
        for (int n = 0; n < 4; ++n)                                          \
            bh[n] = *(const bf16x8*)(lds + (Q) + bbase + n * 512 + kA);      \
        _Pragma("unroll")                                                    \
        for (int m = 0; m < 4; ++m)                                          \
            aa[m] = *(const bf16x8*)(lds + (Q) + abase + m * 512 + kA);      \
        SP1;                                                                 \
        _Pragma("unroll")                                                    \
        for (int m = 0; m < 4; ++m) {                                        \
            _Pragma("unroll")                                                \
            for (int n = 0; n < 4; ++n)                                      \
                acc[m][n] = mfma(aa[m], bh[n], acc[m][n]);                   \
        }                                                                    \
        SP0;                                                                 \
        SYNC;                                                                \
    }

#define STA(t, buf) stage32(Ab + (t) * 32, lds + (buf), tid)
#define STB(t, buf) stage32(Bb + (t) * 32, lds + (buf) + 4096, tid)

DEVI void pipe128(const u16* Ab, const u16* Bb, u16* lds,
                  f32x4 (&acc)[4][4], int tid) {
    const int lane = tid & 63;
    const int wm = (tid >> 6) >> 1, wn = (tid >> 6) & 1;
    const int kA = (((lane >> 4) ^ ((lane >> 1) & 3)) << 3);
    const int abase = (wm * 64 + (lane & 15)) * 32;
    const int bbase = 4096 + (wn * 64 + (lane & 15)) * 32;

    // prologue: T0 -> buf0
    STA(0, 0); STB(0, 0);
    __syncthreads();

#pragma unroll 1
    for (int j = 0; j < 15; ++j) {
        const int T = 2 * j;
        TILE(0,    { STA(T + 1, 8192); STB(T + 1, 8192); }, TCLOSE);
        TILE(8192, { STA(T + 2, 0);    STB(T + 2, 0);    }, TCLOSE);
    }
    TILE(0,    { STA(31, 8192); STB(31, 8192); }, TCLOSE);
    TILE(8192, NOP, NOP);
}

// ------- gate GEMM + fused sigmoid-gate + fused per-chunk scan (scanA) ------
// 128x128 tile: wave (wm,wn) owns rows bm*128+wm*64..+64 (= ONE 64-row
// chunk) x 64 concat-cols (32 channels). Frag n even = gate, odd = inp.

__global__ __launch_bounds__(256, 4) void k_gemm_cat8(
    const u16* __restrict__ A, const u16* __restrict__ Bcat,
    const float* __restrict__ gb, const float* __restrict__ ib,
    u32* __restrict__ ab, float2* __restrict__ cAB) {
    __shared__ __align__(16) u16 lds[16384];     // 32KB -> 4 blocks/CU
    const int tid = threadIdx.x, lane = tid & 63;
    const int wm = (tid >> 6) >> 1, wn = (tid >> 6) & 1;

    // bijective XCD swizzle, grid (16, 128) = 2048 wg
    int fid = (int)blockIdx.y * 16 + (int)blockIdx.x;
    int swz = (fid & 7) * 256 + (fid >> 3);
    const long bn = swz & 15, bm = swz >> 4;

    f32x4 acc[4][4] = {};
    pipe128(A + bm * 128 * 1024, Bcat + bn * 128 * 1024, lds, acc, tid);

    const long rbase = bm * 128 + wm * 64;
    const int chbase = (int)bn * 64 + wn * 32;
    float sA[2][4], sB[2][4];
#pragma unroll
    for (int t = 0; t < 2; ++t) {
        int ch = chbase + t * 16 + (lane & 15);
        float g0 = gb[ch], i0 = ib[ch];
#pragma unroll
        for (int m = 0; m < 4; ++m) {
            long row = rbase + m * 16 + ((lane >> 4) << 2);
            float Aseg = 1.0f, Bseg = 0.0f;
#pragma unroll
            for (int i = 0; i < 4; ++i) {
                float pg = acc[m][2 * t][i] + g0;
                float pi = acc[m][2 * t + 1][i] + i0;
                float aa = 1.0f / (1.0f + __expf(-pg));
                float bb = (1.0f - aa) * pi;
                u16 au = f2bf(aa), bu = f2bf(bb);
                ab[(row + i) * 1024 + ch] = (u32)au | ((u32)bu << 16);
                float ar = bf2f(au), br = bf2f(bu);
                Aseg = ar * Aseg;
                Bseg = ar * Bseg + br;
            }
            sA[t][m] = Aseg;
            sB[t][m] = Bseg;
        }
    }
    // compose the wave's single 64-row chunk: fold m (rows m*16+) then q (+4)
#pragma unroll
    for (int t = 0; t < 2; ++t) {
        float Ac = 1.0f, Bc = 0.0f;
#pragma unroll
        for (int m = 0; m < 4; ++m) {
#pragma unroll
            for (int q = 0; q < 4; ++q) {
                float Aq = __shfl(sA[t][m], (lane & 15) + q * 16);
                float Bq = __shfl(sB[t][m], (lane & 15) + q * 16);
                Ac = Aq * Ac;
                Bc = Aq * Bc + Bq;
            }
        }
        if ((lane >> 4) == 0) {
            long gc = rbase >> 6;                 // = bm*2 + wm
            int ch = chbase + t * 16 + (lane & 15);
            cAB[gc * 1024 + ch] = make_float2(Ac, Bc);
        }
    }
}

// -------- final GEMM: out = h @ out_w + x + out_b (x residual as bf16) ------

__global__ __launch_bounds__(256, 4) void k_gemm_out8(
    const u16* __restrict__ A, const u16* __restrict__ Bt,
    const u16* __restrict__ xbf, const float* __restrict__ ob,
    float* __restrict__ out) {
    __shared__ __align__(16) u16 lds[16384];
    const int tid = threadIdx.x, lane = tid & 63;
    const int wm = (tid >> 6) >> 1, wn = (tid >> 6) & 1;

    // bijective XCD swizzle, grid (8, 128) = 1024 wg
    int fid = (int)blockIdx.y * 8 + (int)blockIdx.x;
    int swz = (fid & 7) * 128 + (fid >> 3);
    const long bn = swz & 7, bm = swz >> 3;

    f32x4 acc[4][4] = {};
    pipe128(A + bm * 128 * 1024, Bt + bn * 128 * 1024, lds, acc, tid);

    const long rbase = bm * 128 + wm * 64;
    const int cbase = (int)bn * 128 + wn * 64;
#pragma unroll
    for (int n = 0; n < 4; ++n) {
        int col = cbase + n * 16 + (lane & 15);
        float o0 = ob[col];
#pragma unroll
        for (int m = 0; m < 4; ++m) {
            long row = rbase + m * 16 + ((lane >> 4) << 2);
#pragma unroll
            for (int i = 0; i < 4; ++i) {
                long o = (row + i) * 1024 + col;
                out[o] = acc[m][n][i] + o0 + bf2f(xbf[o]);
            }
        }
    }
}

// ------------- fused prep: cvt_x + transpose_cat + transpose_bf -------------

__global__ __launch_bounds__(256) void k_prep(
    const float4* __restrict__ x4, uint2* __restrict__ xb2,
    const float* __restrict__ gw, const float* __restrict__ iw,
    u16* __restrict__ catW, const float* __restrict__ ow,
    u16* __restrict__ owT) {
    __shared__ float t[32][33];
    int bid = blockIdx.x;
    if (bid < 16384) {
        int i = bid * 256 + threadIdx.x;
        float4 v = x4[i];
        uint2 r;
        r.x = (u32)f2bf(v.x) | ((u32)f2bf(v.y) << 16);
        r.y = (u32)f2bf(v.z) | ((u32)f2bf(v.w) << 16);
        xb2[i] = r;
        return;
    }
    int xi = threadIdx.x & 31, y = threadIdx.x >> 5;
    if (bid < 18432) {
        int q = bid - 16384;
        int c0 = (q & 31) * 32, r0 = ((q >> 5) & 31) * 32, z = q >> 10;
        const float* w = z ? iw : gw;
        for (int i = y; i < 32; i += 8) t[i][xi] = w[(size_t)(r0 + i) * 1024 + c0 + xi];
        __syncthreads();
        for (int i = y; i < 32; i += 8) {
            int ch = c0 + i;
            int r = ((ch >> 4) << 5) | (z << 4) | (ch & 15);
            catW[(size_t)r * 1024 + r0 + xi] = f2bf(t[xi][i]);
        }
    } else {
        int q = bid - 18432;
        int c0 = (q & 31) * 32, r0 = (q >> 5) * 32;
        for (int i = y; i < 32; i += 8) t[i][xi] = ow[(size_t)(r0 + i) * 1024 + c0 + xi];
        __syncthreads();
        for (int i = y; i < 32; i += 8)
            owT[(size_t)(c0 + i) * 1024 + r0 + xi] = f2bf(t[xi][i]);
    }
}

// ---------------- chunked affine scan phases B & C ----------------

__global__ __launch_bounds__(256) void k_scanB(const float2* __restrict__ cAB,
                                               float* __restrict__ hin) {
    int e = blockIdx.x * 256 + threadIdx.x;
    int bt = blockIdx.y;
    float H = 0.f;
#pragma unroll
    for (int c = 0; c < 64; ++c) {
        long s = ((long)bt * 64 + c) * 1024 + e;
        hin[s] = H;
        float2 v = cAB[s];
        H = v.x * H + v.y;
    }
}

__global__ __launch_bounds__(256) void k_scanC(const u32* __restrict__ ab,
                                               const float* __restrict__ hin,
                                               u16* __restrict__ hout) {
    int e = blockIdx.x * 256 + threadIdx.x;
    int c = blockIdx.y, bt = blockIdx.z;
    long base = ((long)bt * 4096 + c * 64) * 1024 + e;
    float H = hin[((long)bt * 64 + c) * 1024 + e];
#pragma unroll 4
    for (int i = 0; i < 64; ++i) {
        u32 v = ab[base + (long)i * 1024];
        H = bf2f((u16)v) * H + bf2f((u16)(v >> 16));
        hout[base + (long)i * 1024] = f2bf(H);
    }
}

// ---------------- launch ----------------

extern "C" void kernel_launch(void* const* d_in, const int* in_sizes, int n_in,
                              void* d_out, int out_size, void* d_ws, size_t ws_size,
                              hipStream_t stream) {
    const float* x      = (const float*)d_in[0];
    const float* gate_w = (const float*)d_in[1];
    const float* gate_b = (const float*)d_in[2];
    const float* inp_w  = (const float*)d_in[3];
    const float* inp_b  = (const float*)d_in[4];
    const float* out_w  = (const float*)d_in[5];
    const float* out_b  = (const float*)d_in[6];
    float* out = (float*)d_out;

    const int Bsz = 4, S = 4096, Din = 1024, Dst = 1024;
    const int M = Bsz * S;                 // 16384

    // workspace layout (bytes)
    char* w = (char*)d_ws;
    u16* xb      = (u16*)(w);                // 33,554,432  x bf16
    u16* catW    = (u16*)(w + 33554432);     //  4,194,304  [gate;inp] interleaved ^T
    u16* owT     = (u16*)(w + 37748736);     //  2,097,152  out_w^T bf16
    u16* hbf     = (u16*)(w + 39845888);     // 33,554,432  scan_out bf16
    float2* cAB  = (float2*)(w + 73400320);  //  2,097,152  chunk (A,H) pairs
    float* hin   = (float*)(w + 75497472);   //  1,048,576  chunk incoming states
    // total 76,546,048 B

    // packed ab lives in d_out (67,108,864 B); overwritten by final GEMM.
    u32* ab = (u32*)d_out;

    // 1. fused prep (cvt + both transposes)
    k_prep<<<19456, 256, 0, stream>>>((const float4*)x, (uint2*)xb,
                                      gate_w, inp_w, catW, out_w, owT);

    // 2. fused concat GEMM -> packed ab + per-chunk scan composition
    k_gemm_cat8<<<dim3(16, M / 128), 256, 0, stream>>>(xb, catW, gate_b, inp_b, ab, cAB);

    // 3. scan combine + replay -> h (bf16)
    k_scanB<<<dim3(4, Bsz), 256, 0, stream>>>(cAB, hin);
    k_scanC<<<dim3(4, 64, Bsz), 256, 0, stream>>>(ab, hin, hbf);

    // 4. final GEMM: out = h @ out_w + x + out_b
    k_gemm_out8<<<dim3(8, M / 128), 256, 0, stream>>>(hbf, owT, xb, out_b, out);
}

// Round 26
// 162.183 us; speedup vs baseline: 1.1372x; 1.1372x over previous
//
#include <hip/hip_runtime.h>

typedef unsigned short u16;
typedef unsigned int   u32;
typedef __bf16 bf16x8 __attribute__((ext_vector_type(8)));
typedef float  f32x4  __attribute__((ext_vector_type(4)));

#define DEVI __device__ __forceinline__

DEVI u16 f2bf(float f) {
    union { float f; u32 u; } c; c.f = f;
    u32 u = c.u;
    u32 r = (u + 0x7fffu + ((u >> 16) & 1u)) >> 16;
    return (u16)r;
}
DEVI float bf2f(u16 v) {
    union { u32 u; float f; } c; c.u = ((u32)v) << 16;
    return c.f;
}

DEVI void gload16(const void* g, void* l) {
    __builtin_amdgcn_global_load_lds(
        (const __attribute__((address_space(1))) void*)g,
        (__attribute__((address_space(3))) void*)l, 16, 0, 0);
}

// ------------- 128x128 GEMM, BK=64, 256 threads, 2 blocks/CU -------------
// Best measured configuration (r23, 162.6us total). 3-bit swizzle
// (conflicts = 0 measured); one __syncthreads per K-tile; stage-first into
// the opposite buffer; setprio around MFMA; 2 co-resident blocks.
// Buffer q at q*16384 u16 (32KB): A half [128 rows][64 K] @+0 (8192 u16),
// B half @+8192. Swizzle: physical 16B chunk p holds logical p^(row&7);
// stage source ks=((tid&7)^((tid>>3)&7))<<3; reads kA=((lane>>4)^(lane&7))<<3,
// kB=kA^32 (all frag-row offsets are multiples of 8 -> row&7 == lane&7).

#define SP1     __builtin_amdgcn_s_setprio(1)
#define SP0     __builtin_amdgcn_s_setprio(0)

// stage one 16KB half ([128 rows][64 K] bf16) with 256 threads: 4 x 16B.
DEVI void stage128(const u16* g, u16* slot, int tid) {
    const int ks = (((tid & 7) ^ ((tid >> 3) & 7)) << 3);
#pragma unroll
    for (int j = 0; j < 4; ++j) {
        const int r = j * 32 + (tid >> 3);
        gload16(g + (long)r * 1024 + ks, slot + j * 2048 + tid * 8);
    }
}

DEVI f32x4 mfma(const bf16x8& a, const bf16x8& b, const f32x4& c) {
    return __builtin_amdgcn_mfma_f32_16x16x32_bf16(a, b, c, 0, 0, 0);
}

#define NOP do {} while (0)
#define TCLOSE { __syncthreads(); }

// one K-tile from buffer base Q: stage first, 16 reads, 32 MFMA, sync.
#define TILE(Q, STG, SYNC)                                                   \
    {                                                                        \
        STG;                                                                 \
        bf16x8 bh0[4], bh1[4], aa0[4], aa1[4];                               \
        _Pragma("unroll")                                                    \
        for (int n = 0; n < 4; ++n) {                                        \
            bh0[n] = *(const bf16x8*)(lds + (Q) + bbase + n * 1024 + kA);    \
            bh1[n] = *(const bf16x8*)(lds + (Q) + bbase + n * 1024 + kB);    \
        }                                                                    \
        _Pragma("unroll")                                                    \
        for (int m = 0; m < 4; ++m) {                                        \
            aa0[m] = *(const bf16x8*)(lds + (Q) + abase + m * 1024 + kA);    \
            aa1[m] = *(const bf16x8*)(lds + (Q) + abase + m * 1024 + kB);    \
        }                                                                    \
        SP1;                                                                 \
        _Pragma("unroll")                                                    \
        for (int m = 0; m < 4; ++m) {                                        \
            _Pragma("unroll")                                                \
            for (int n = 0; n < 4; ++n) {                                    \
                acc[m][n] = mfma(aa0[m], bh0[n], acc[m][n]);                 \
                acc[m][n] = mfma(aa1[m], bh1[n], acc[m][n]);                 \
            }                                                                \
        }                                                                    \
        SP0;                                                                 \
        SYNC;                                                                \
    }

#define STA(t, buf) stage128(Ab + (t) * 64, lds + (buf), tid)
#define STB(t, buf) stage128(Bb + (t) * 64, lds + (buf) + 8192, tid)

DEVI void pipe128(const u16* Ab, const u16* Bb, u16* lds,
                  f32x4 (&acc)[4][4], int tid) {
    const int lane = tid & 63;
    const int wm = (tid >> 6) >> 1, wn = (tid >> 6) & 1;
    const int kA = (((lane >> 4) ^ (lane & 7)) << 3);
    const int kB = kA ^ 32;
    const int abase = wm * 4096 + (lane & 15) * 64;
    const int bbase = 8192 + wn * 4096 + (lane & 15) * 64;

    // prologue: T0 -> buf0
    STA(0, 0); STB(0, 0);
    __syncthreads();

#pragma unroll 1
    for (int j = 0; j < 7; ++j) {
        const int T = 2 * j;
        TILE(0,     { STA(T + 1, 16384); STB(T + 1, 16384); }, TCLOSE);
        TILE(16384, { STA(T + 2, 0);     STB(T + 2, 0);     }, TCLOSE);
    }
    TILE(0,     { STA(15, 16384); STB(15, 16384); }, TCLOSE);
    TILE(16384, NOP, NOP);
}

// ------- gate GEMM + fused sigmoid-gate + fused per-chunk scan (scanA) ------
// 128x128 tile: wave (wm,wn) owns rows bm*128+wm*64..+64 (= ONE 64-row
// chunk) x 64 concat-cols (32 channels). Frag n even = gate, odd = inp.

__global__ __launch_bounds__(256, 2) void k_gemm_cat8(
    const u16* __restrict__ A, const u16* __restrict__ Bcat,
    const float* __restrict__ gb, const float* __restrict__ ib,
    u32* __restrict__ ab, float2* __restrict__ cAB) {
    __shared__ __align__(16) u16 lds[32768];     // 64KB -> 2 blocks/CU
    const int tid = threadIdx.x, lane = tid & 63;
    const int wm = (tid >> 6) >> 1, wn = (tid >> 6) & 1;

    // bijective XCD swizzle, grid (16, 128) = 2048 wg
    int fid = (int)blockIdx.y * 16 + (int)blockIdx.x;
    int swz = (fid & 7) * 256 + (fid >> 3);
    const long bn = swz & 15, bm = swz >> 4;

    f32x4 acc[4][4] = {};
    pipe128(A + bm * 128 * 1024, Bcat + bn * 128 * 1024, lds, acc, tid);

    const long rbase = bm * 128 + wm * 64;
    const int chbase = (int)bn * 64 + wn * 32;
    float sA[2][4], sB[2][4];
#pragma unroll
    for (int t = 0; t < 2; ++t) {
        int ch = chbase + t * 16 + (lane & 15);
        float g0 = gb[ch], i0 = ib[ch];
#pragma unroll
        for (int m = 0; m < 4; ++m) {
            long row = rbase + m * 16 + ((lane >> 4) << 2);
            float Aseg = 1.0f, Bseg = 0.0f;
#pragma unroll
            for (int i = 0; i < 4; ++i) {
                float pg = acc[m][2 * t][i] + g0;
                float pi = acc[m][2 * t + 1][i] + i0;
                float aa = 1.0f / (1.0f + __expf(-pg));
                float bb = (1.0f - aa) * pi;
                u16 au = f2bf(aa), bu = f2bf(bb);
                ab[(row + i) * 1024 + ch] = (u32)au | ((u32)bu << 16);
                float ar = bf2f(au), br = bf2f(bu);
                Aseg = ar * Aseg;
                Bseg = ar * Bseg + br;
            }
            sA[t][m] = Aseg;
            sB[t][m] = Bseg;
        }
    }
    // compose the wave's single 64-row chunk: fold m (rows m*16+) then q (+4)
#pragma unroll
    for (int t = 0; t < 2; ++t) {
        float Ac = 1.0f, Bc = 0.0f;
#pragma unroll
        for (int m = 0; m < 4; ++m) {
#pragma unroll
            for (int q = 0; q < 4; ++q) {
                float Aq = __shfl(sA[t][m], (lane & 15) + q * 16);
                float Bq = __shfl(sB[t][m], (lane & 15) + q * 16);
                Ac = Aq * Ac;
                Bc = Aq * Bc + Bq;
            }
        }
        if ((lane >> 4) == 0) {
            long gc = rbase >> 6;                 // = bm*2 + wm
            int ch = chbase + t * 16 + (lane & 15);
            cAB[gc * 1024 + ch] = make_float2(Ac, Bc);
        }
    }
}

// -------- final GEMM: out = h @ out_w + x + out_b (x residual as bf16) ------

__global__ __launch_bounds__(256, 2) void k_gemm_out8(
    const u16* __restrict__ A, const u16* __restrict__ Bt,
    const u16* __restrict__ xbf, const float* __restrict__ ob,
    float* __restrict__ out) {
    __shared__ __align__(16) u16 lds[32768];
    const int tid = threadIdx.x, lane = tid & 63;
    const int wm = (tid >> 6) >> 1, wn = (tid >> 6) & 1;

    // bijective XCD swizzle, grid (8, 128) = 1024 wg
    int fid = (int)blockIdx.y * 8 + (int)blockIdx.x;
    int swz = (fid & 7) * 128 + (fid >> 3);
    const long bn = swz & 7, bm = swz >> 3;

    f32x4 acc[4][4] = {};
    pipe128(A + bm * 128 * 1024, Bt + bn * 128 * 1024, lds, acc, tid);

    const long rbase = bm * 128 + wm * 64;
    const int cbase = (int)bn * 128 + wn * 64;
#pragma unroll
    for (int n = 0; n < 4; ++n) {
        int col = cbase + n * 16 + (lane & 15);
        float o0 = ob[col];
#pragma unroll
        for (int m = 0; m < 4; ++m) {
            long row = rbase + m * 16 + ((lane >> 4) << 2);
#pragma unroll
            for (int i = 0; i < 4; ++i) {
                long o = (row + i) * 1024 + col;
                out[o] = acc[m][n][i] + o0 + bf2f(xbf[o]);
            }
        }
    }
}

// ------------- fused prep: cvt_x + transpose_cat + transpose_bf -------------

__global__ __launch_bounds__(256) void k_prep(
    const float4* __restrict__ x4, uint2* __restrict__ xb2,
    const float* __restrict__ gw, const float* __restrict__ iw,
    u16* __restrict__ catW, const float* __restrict__ ow,
    u16* __restrict__ owT) {
    __shared__ float t[32][33];
    int bid = blockIdx.x;
    if (bid < 16384) {
        int i = bid * 256 + threadIdx.x;
        float4 v = x4[i];
        uint2 r;
        r.x = (u32)f2bf(v.x) | ((u32)f2bf(v.y) << 16);
        r.y = (u32)f2bf(v.z) | ((u32)f2bf(v.w) << 16);
        xb2[i] = r;
        return;
    }
    int xi = threadIdx.x & 31, y = threadIdx.x >> 5;
    if (bid < 18432) {
        int q = bid - 16384;
        int c0 = (q & 31) * 32, r0 = ((q >> 5) & 31) * 32, z = q >> 10;
        const float* w = z ? iw : gw;
        for (int i = y; i < 32; i += 8) t[i][xi] = w[(size_t)(r0 + i) * 1024 + c0 + xi];
        __syncthreads();
        for (int i = y; i < 32; i += 8) {
            int ch = c0 + i;
            int r = ((ch >> 4) << 5) | (z << 4) | (ch & 15);
            catW[(size_t)r * 1024 + r0 + xi] = f2bf(t[xi][i]);
        }
    } else {
        int q = bid - 18432;
        int c0 = (q & 31) * 32, r0 = (q >> 5) * 32;
        for (int i = y; i < 32; i += 8) t[i][xi] = ow[(size_t)(r0 + i) * 1024 + c0 + xi];
        __syncthreads();
        for (int i = y; i < 32; i += 8)
            owT[(size_t)(c0 + i) * 1024 + r0 + xi] = f2bf(t[xi][i]);
    }
}

// ---------------- chunked affine scan phases B & C ----------------

__global__ __launch_bounds__(256) void k_scanB(const float2* __restrict__ cAB,
                                               float* __restrict__ hin) {
    int e = blockIdx.x * 256 + threadIdx.x;
    int bt = blockIdx.y;
    float H = 0.f;
#pragma unroll
    for (int c = 0; c < 64; ++c) {
        long s = ((long)bt * 64 + c) * 1024 + e;
        hin[s] = H;
        float2 v = cAB[s];
        H = v.x * H + v.y;
    }
}

__global__ __launch_bounds__(256) void k_scanC(const u32* __restrict__ ab,
                                               const float* __restrict__ hin,
                                               u16* __restrict__ hout) {
    int e = blockIdx.x * 256 + threadIdx.x;
    int c = blockIdx.y, bt = blockIdx.z;
    long base = ((long)bt * 4096 + c * 64) * 1024 + e;
    float H = hin[((long)bt * 64 + c) * 1024 + e];
#pragma unroll 4
    for (int i = 0; i < 64; ++i) {
        u32 v = ab[base + (long)i * 1024];
        H = bf2f((u16)v) * H + bf2f((u16)(v >> 16));
        hout[base + (long)i * 1024] = f2bf(H);
    }
}

// ---------------- launch ----------------

extern "C" void kernel_launch(void* const* d_in, const int* in_sizes, int n_in,
                              void* d_out, int out_size, void* d_ws, size_t ws_size,
                              hipStream_t stream) {
    const float* x      = (const float*)d_in[0];
    const float* gate_w = (const float*)d_in[1];
    const float* gate_b = (const float*)d_in[2];
    const float* inp_w  = (const float*)d_in[3];
    const float* inp_b  = (const float*)d_in[4];
    const float* out_w  = (const float*)d_in[5];
    const float* out_b  = (const float*)d_in[6];
    float* out = (float*)d_out;

    const int Bsz = 4, S = 4096, Din = 1024, Dst = 1024;
    const int M = Bsz * S;                 // 16384

    // workspace layout (bytes)
    char* w = (char*)d_ws;
    u16* xb      = (u16*)(w);                // 33,554,432  x bf16
    u16* catW    = (u16*)(w + 33554432);     //  4,194,304  [gate;inp] interleaved ^T
    u16* owT     = (u16*)(w + 37748736);     //  2,097,152  out_w^T bf16
    u16* hbf     = (u16*)(w + 39845888);     // 33,554,432  scan_out bf16
    float2* cAB  = (float2*)(w + 73400320);  //  2,097,152  chunk (A,H) pairs
    float* hin   = (float*)(w + 75497472);   //  1,048,576  chunk incoming states
    // total 76,546,048 B

    // packed ab lives in d_out (67,108,864 B); overwritten by final GEMM.
    u32* ab = (u32*)d_out;

    // 1. fused prep (cvt + both transposes)
    k_prep<<<19456, 256, 0, stream>>>((const float4*)x, (uint2*)xb,
                                      gate_w, inp_w, catW, out_w, owT);

    // 2. fused concat GEMM -> packed ab + per-chunk scan composition
    k_gemm_cat8<<<dim3(16, M / 128), 256, 0, stream>>>(xb, catW, gate_b, inp_b, ab, cAB);

    // 3. scan combine + replay -> h (bf16)
    k_scanB<<<dim3(4, Bsz), 256, 0, stream>>>(cAB, hin);
    k_scanC<<<dim3(4, 64, Bsz), 256, 0, stream>>>(ab, hin, hbf);

    // 4. final GEMM: out = h @ out_w + x + out_b
    k_gemm_out8<<<dim3(8, M / 128), 256, 0, stream>>>(hbf, owT, xb, out_b, out);
}